// Round 9
// baseline (55.126 us; speedup 1.0000x reference)
//
#include <hip/hip_runtime.h>
#include <hip/hip_bf16.h>

#define STUN   50000
#define BATCH  4096
#define LOG2E  1.4426950408889634f

__device__ __forceinline__ float fexp2(float x){ return __builtin_amdgcn_exp2f(x); }
__device__ __forceinline__ float frcp (float x){ return __builtin_amdgcn_rcpf(x); }
__device__ __forceinline__ float fsig (float x){ return frcp(1.0f + fexp2(-LOG2E * x)); }

// ---------------------------------------------------------------------------
// K0: weight repack (float4-interleaved) + E-matrix precompute (interleaved).
//   kle4 [u4=16][idx=128][4]  = kle[idx][u4*4+c]
//   fc1i/fc2i [u4=48][128][4] = fcW[idx][u4*4+c]
//   W1ai/W2ai [u4=32][128][4] = W[idx][u4*4+c]        (the 'a' half, u<128)
//   E1i/E2i  [j4=32][k=128][4]= exp2(-log2e * sum_t kle[k][t]*W[j4*4+c][128+t])
// grid 432 blocks x 128 threads
// ---------------------------------------------------------------------------
__global__ __launch_bounds__(128) void k_pre(
    const float* __restrict__ kle,
    const float* __restrict__ W1,
    const float* __restrict__ W2,
    const float* __restrict__ fc1_W,
    const float* __restrict__ fc2_W,
    float* __restrict__ kle4,
    float* __restrict__ fc1i,
    float* __restrict__ fc2i,
    float* __restrict__ W1ai,
    float* __restrict__ W2ai,
    float* __restrict__ E1i,
    float* __restrict__ E2i)
{
    const int bid = blockIdx.x;
    const int t   = threadIdx.x;   // 0..127
    if (bid < 16) {
        const int u4 = bid;
        float4 v;
        v.x = kle[t * 64 + u4 * 4 + 0];
        v.y = kle[t * 64 + u4 * 4 + 1];
        v.z = kle[t * 64 + u4 * 4 + 2];
        v.w = kle[t * 64 + u4 * 4 + 3];
        *(float4*)&kle4[(u4 * 128 + t) * 4] = v;
    } else if (bid < 64) {
        const int u4 = bid - 16;
        float4 v;
        v.x = fc1_W[t * 192 + u4 * 4 + 0];
        v.y = fc1_W[t * 192 + u4 * 4 + 1];
        v.z = fc1_W[t * 192 + u4 * 4 + 2];
        v.w = fc1_W[t * 192 + u4 * 4 + 3];
        *(float4*)&fc1i[(u4 * 128 + t) * 4] = v;
    } else if (bid < 112) {
        const int u4 = bid - 64;
        float4 v;
        v.x = fc2_W[t * 192 + u4 * 4 + 0];
        v.y = fc2_W[t * 192 + u4 * 4 + 1];
        v.z = fc2_W[t * 192 + u4 * 4 + 2];
        v.w = fc2_W[t * 192 + u4 * 4 + 3];
        *(float4*)&fc2i[(u4 * 128 + t) * 4] = v;
    } else if (bid < 144) {
        const int u4 = bid - 112;
        float4 v;
        v.x = W1[t * 192 + u4 * 4 + 0];
        v.y = W1[t * 192 + u4 * 4 + 1];
        v.z = W1[t * 192 + u4 * 4 + 2];
        v.w = W1[t * 192 + u4 * 4 + 3];
        *(float4*)&W1ai[(u4 * 128 + t) * 4] = v;
    } else if (bid < 176) {
        const int u4 = bid - 144;
        float4 v;
        v.x = W2[t * 192 + u4 * 4 + 0];
        v.y = W2[t * 192 + u4 * 4 + 1];
        v.z = W2[t * 192 + u4 * 4 + 2];
        v.w = W2[t * 192 + u4 * 4 + 3];
        *(float4*)&W2ai[(u4 * 128 + t) * 4] = v;
    } else if (bid < 304) {
        const int j = bid - 176;          // lane t = k
        float acc = 0.f;
        #pragma unroll
        for (int u4 = 0; u4 < 16; ++u4) {
            const float4 kv = *(const float4*)&kle[t * 64 + u4 * 4];
            const float4 wv = *(const float4*)&W1[j * 192 + 128 + u4 * 4];
            acc += kv.x * wv.x + kv.y * wv.y + kv.z * wv.z + kv.w * wv.w;
        }
        E1i[((j >> 2) * 128 + t) * 4 + (j & 3)] = fexp2(-LOG2E * acc);
    } else {
        const int j = bid - 304;
        float acc = 0.f;
        #pragma unroll
        for (int u4 = 0; u4 < 16; ++u4) {
            const float4 kv = *(const float4*)&kle[t * 64 + u4 * 4];
            const float4 wv = *(const float4*)&W2[j * 192 + 128 + u4 * 4];
            acc += kv.x * wv.x + kv.y * wv.y + kv.z * wv.z + kv.w * wv.w;
        }
        E2i[((j >> 2) * 128 + t) * 4 + (j & 3)] = fexp2(-LOG2E * acc);
    }
}

// ---------------------------------------------------------------------------
// K_FUSED v5: ONE hot kernel. 4 batch elems/block, 256 threads, grid 1024.
// launch_bounds(256,6): VGPR cap ~84 (no spill regime), 6 blocks/CU.
// Prep: 256 threads = (half, idx), acc[4], full u-range (no split/partials).
// es stays in LDS (no HBM round trip).
// Main: wave w -> kh=w&1, jh=w>>1; thread: 4 b x 64 j x 1 k.
//   u = es1*E1, v = es2*E2, acc += (v-u)*rcp((1+u)(1+v))*w3   (1 trans/pair)
// LDS ~19 KB.
// ---------------------------------------------------------------------------
__global__ __launch_bounds__(256, 6) void k_fused(
    const int*   __restrict__ stu_id,
    const int*   __restrict__ exer_id,
    const float* __restrict__ student_emb,   // (2*50000, 64) flat
    const float* __restrict__ prompt_stu,    // (50000, 64)
    const float* __restrict__ k_diff,        // (20000, 64)
    const float* __restrict__ s_exer,        // (2, 64)
    const float* __restrict__ kle4,
    const float* __restrict__ fc1i,
    const float* __restrict__ fc2i,
    const float* __restrict__ W1ai,
    const float* __restrict__ W2ai,
    const float* __restrict__ fc1_b,
    const float* __restrict__ fc2_b,
    const float* __restrict__ E1i,    // [j4=32][k=128][4] = exp2(A')
    const float* __restrict__ E2i,
    const float* __restrict__ W3,
    const float* __restrict__ b3,
    const float* __restrict__ kn,
    float* __restrict__ out)
{
    __shared__ __align__(16) float sh_in [4][64][4];    // 4 KB
    __shared__ __align__(16) float sh_old[2][128][4];   // 4 KB
    __shared__ __align__(16) float sh_e  [2][128][4];   // 4 KB
    __shared__ __align__(16) float ses   [2][4][128];   // 4 KB [mat][b][j]
    __shared__ float sW3[128];
    __shared__ __align__(16) float redj[2][64][4];      // 2 KB [kh][lane][b]
    __shared__ float red2_o[2][4];
    __shared__ float red2_k[2][4];

    const int t  = threadIdx.x;           // 0..255
    const int b0 = blockIdx.x * 4;

    // ---- gather phase: 64 threads per local batch elem, coalesced ----
    {
        const int g   = t >> 6;
        const int u   = t & 63;
        const int sid = stu_id[b0 + g];
        const int eid = exer_id[b0 + g];
        const int er  = (eid >= 10000) ? 1 : 0;
        sh_in[0][u][g] = student_emb[sid * 64 + u];
        sh_in[1][u][g] = fsig(k_diff[eid * 64 + u]);
        sh_in[2][u][g] = prompt_stu[(sid % STUN) * 64 + u];
        sh_in[3][u][g] = fsig(s_exer[er * 64 + u]);
    }
    if (t < 32) *(float4*)&sW3[t * 4] = *(const float4*)&W3[t * 4];
    __syncthreads();

    const int half = t >> 7;
    const int idx  = t & 127;

    float acc[4];

#define FMA4(xbase) { \
        const float4 x0 = *(const float4*)&(xbase)[0]; \
        acc[0] += wv * x0.x; acc[1] += wv * x0.y; acc[2] += wv * x0.z; acc[3] += wv * x0.w; }

#define WSTEP(WARR, XARR, u4) { \
        const float4 w4 = *(const float4*)&WARR[((u4) * 128 + idx) * 4]; \
        { const float wv = w4.x; FMA4(XARR[(u4)*4+0]); } \
        { const float wv = w4.y; FMA4(XARR[(u4)*4+1]); } \
        { const float wv = w4.z; FMA4(XARR[(u4)*4+2]); } \
        { const float wv = w4.w; FMA4(XARR[(u4)*4+3]); } }

#define WSTEPO(WARR, XARR, u4, uoff) { \
        const float4 w4 = *(const float4*)&WARR[((u4) * 128 + idx) * 4]; \
        { const float wv = w4.x; FMA4(XARR[((u4)-(uoff))*4+0]); } \
        { const float wv = w4.y; FMA4(XARR[((u4)-(uoff))*4+1]); } \
        { const float wv = w4.z; FMA4(XARR[((u4)-(uoff))*4+2]); } \
        { const float wv = w4.w; FMA4(XARR[((u4)-(uoff))*4+3]); } }

    // ---- stage 1: old[k] = sig( dot(row, kle[k]) ) ----
    #pragma unroll
    for (int b = 0; b < 4; ++b) acc[b] = 0.f;
    #pragma unroll 4
    for (int u4 = 0; u4 < 16; ++u4) WSTEP(kle4, sh_in[half], u4);
    #pragma unroll
    for (int b = 0; b < 4; ++b) sh_old[half][idx][b] = fsig(acc[b]);
    __syncthreads();

    // ---- stage 2: e[i] = sig( [p, old] @ fcW[i] + fcb[i] ) ----
    {
        const float* fcT = half ? fc2i : fc1i;
        #pragma unroll
        for (int b = 0; b < 4; ++b) acc[b] = 0.f;
        #pragma unroll 4
        for (int u4 = 0; u4 < 16; ++u4) WSTEP(fcT, sh_in[2 + half], u4);
        #pragma unroll 4
        for (int u4 = 16; u4 < 48; ++u4) WSTEPO(fcT, sh_old[half], u4, 16);
        const float bias = (half ? fc2_b : fc1_b)[idx];
        #pragma unroll
        for (int b = 0; b < 4; ++b) sh_e[half][idx][b] = fsig(acc[b] + bias);
    }
    __syncthreads();

    // ---- stage 3: es[b][j] = exp2(-log2e * dot(e, Wa[j])) -> LDS ----
    {
        const float* WT = half ? W2ai : W1ai;
        #pragma unroll
        for (int b = 0; b < 4; ++b) acc[b] = 0.f;
        #pragma unroll 4
        for (int u4 = 0; u4 < 32; ++u4) WSTEP(WT, sh_e[half], u4);
        #pragma unroll
        for (int b = 0; b < 4; ++b)
            ses[half][b][idx] = fexp2(-LOG2E * acc[b]);
    }
#undef FMA4
#undef WSTEP
#undef WSTEPO
    __syncthreads();

    // ---- main loop: wave w -> (kh, jh); thread: 4 b x 64 j x 1 k ----
    const int w   = t >> 6;
    const int kk  = t & 63;
    const int kh  = w & 1;
    const int jh  = w >> 1;
    const int k2  = kh * 64 + kk;

    const float4* E1v = (const float4*)E1i;   // [j4*128 + k]
    const float4* E2v = (const float4*)E2i;

    float ac0 = 0.f, ac1 = 0.f, ac2 = 0.f, ac3 = 0.f;

#define COMP(acc, esv1, esv2, e1c, e2c, w3c) { \
        const float uu = (esv1) * (e1c); \
        const float vv = (esv2) * (e2c); \
        const float dd = frcp((1.f + uu) * (1.f + vv)); \
        acc += ((vv - uu) * dd) * (w3c); }

    #pragma unroll 2
    for (int j4 = 0; j4 < 16; ++j4) {
        const int jj4 = jh * 16 + j4;
        const int j   = jj4 * 4;
        const float4 e1 = E1v[jj4 * 128 + k2];
        const float4 e2 = E2v[jj4 * 128 + k2];
        const float4 w3 = *(const float4*)&sW3[j];

#define BODY(acc, bi) { \
        const float4 s1 = *(const float4*)&ses[0][bi][j]; \
        const float4 s2 = *(const float4*)&ses[1][bi][j]; \
        COMP(acc, s1.x, s2.x, e1.x, e2.x, w3.x); \
        COMP(acc, s1.y, s2.y, e1.y, e2.y, w3.y); \
        COMP(acc, s1.z, s2.z, e1.z, e2.z, w3.z); \
        COMP(acc, s1.w, s2.w, e1.w, e2.w, w3.w); }

        BODY(ac0, 0);
        BODY(ac1, 1);
        BODY(ac2, 2);
        BODY(ac3, 3);
#undef BODY
    }
#undef COMP

    // ---- epilogue: combine j-halves, outer sigmoid, kn-weighted k-mean ----
    if (jh == 1) {
        redj[kh][kk][0] = ac0; redj[kh][kk][1] = ac1;
        redj[kh][kk][2] = ac2; redj[kh][kk][3] = ac3;
    }
    __syncthreads();
    if (jh == 0) {
        const float bb3 = b3[0];
        const float4 other = *(const float4*)&redj[kh][kk][0];
        float to[4] = { ac0 + other.x, ac1 + other.y, ac2 + other.z, ac3 + other.w };
        float co[4], ck[4];
        #pragma unroll
        for (int i = 0; i < 4; ++i) {
            const float o   = fsig(to[i] + bb3);
            const float knv = kn[(b0 + i) * 128 + k2];
            co[i] = o * knv;
            ck[i] = knv;
        }
        #pragma unroll
        for (int off = 1; off < 64; off <<= 1) {
            #pragma unroll
            for (int i = 0; i < 4; ++i) {
                co[i] += __shfl_xor(co[i], off);
                ck[i] += __shfl_xor(ck[i], off);
            }
        }
        if (kk == 0) {
            #pragma unroll
            for (int i = 0; i < 4; ++i) {
                red2_o[kh][i] = co[i];
                red2_k[kh][i] = ck[i];
            }
        }
    }
    __syncthreads();
    if (t < 4) {
        const float so = red2_o[0][t] + red2_o[1][t];
        const float sk = red2_k[0][t] + red2_k[1][t];
        out[b0 + t] = so / sk;
    }
}

// ---------------------------------------------------------------------------
extern "C" void kernel_launch(void* const* d_in, const int* in_sizes, int n_in,
                              void* d_out, int out_size, void* d_ws, size_t ws_size,
                              hipStream_t stream)
{
    const int*   stu_id      = (const int*)  d_in[0];
    const int*   exer_id     = (const int*)  d_in[1];
    const float* kn_emb      = (const float*)d_in[2];
    const float* student_emb = (const float*)d_in[3];
    const float* prompt_stu  = (const float*)d_in[4];
    const float* kle         = (const float*)d_in[5];
    const float* k_diff      = (const float*)d_in[6];
    const float* s_exer      = (const float*)d_in[7];
    const float* W1          = (const float*)d_in[8];
    const float* W2          = (const float*)d_in[9];
    const float* W3          = (const float*)d_in[10];
    const float* b3          = (const float*)d_in[11];
    const float* fc1_W       = (const float*)d_in[12];
    const float* fc1_b       = (const float*)d_in[13];
    const float* fc2_W       = (const float*)d_in[14];
    const float* fc2_b       = (const float*)d_in[15];
    float* out = (float*)d_out;

    float* ws   = (float*)d_ws;
    float* kle4 = ws;                        // 16*128*4  = 8192
    float* fc1i = kle4 + 8192;               // 48*128*4  = 24576
    float* fc2i = fc1i + 24576;
    float* W1ai = fc2i + 24576;              // 32*128*4  = 16384
    float* W2ai = W1ai + 16384;
    float* E1i  = W2ai + 16384;              // 32*128*4  = 16384
    float* E2i  = E1i  + 16384;

    k_pre<<<432, 128, 0, stream>>>(kle, W1, W2, fc1_W, fc2_W,
                                   kle4, fc1i, fc2i, W1ai, W2ai, E1i, E2i);
    k_fused<<<BATCH / 4, 256, 0, stream>>>(stu_id, exer_id, student_emb, prompt_stu,
                                           k_diff, s_exer, kle4, fc1i, fc2i,
                                           W1ai, W2ai, fc1_b, fc2_b,
                                           E1i, E2i, W3, b3, kn_emb, out);
}